// Round 1
// baseline (700.171 us; speedup 1.0000x reference)
//
#include <hip/hip_runtime.h>
#include <hip/hip_bf16.h>

typedef unsigned short u16;
typedef __attribute__((ext_vector_type(8))) short frag8;   // 8 bf16
typedef __attribute__((ext_vector_type(4))) float facc4;   // 4 f32

#define L_SEQ 2048
#define D_MODEL 2048
#define N_HEADS 16
#define HEAD_D 128
#define N_QKV 6144
#define D_INNER 8192

__device__ __forceinline__ u16 f2b(float f) {
    __hip_bfloat16 h = __float2bfloat16(f);
    return *reinterpret_cast<u16*>(&h);
}

__device__ __forceinline__ void gload_lds16(const void* g, void* l) {
    __builtin_amdgcn_global_load_lds(
        (const __attribute__((address_space(1))) unsigned int*)g,
        (__attribute__((address_space(3))) unsigned int*)l, 16, 0, 0);
}

__device__ __forceinline__ float gelu_exact(float x) {
    return 0.5f * x * (1.0f + erff(x * 0.7071067811865475f));
}

// ---------------- elementwise f32 -> bf16 ----------------
__global__ void cvt_bf16_kernel(const float* __restrict__ in, u16* __restrict__ out, int n) {
    int i = blockIdx.x * blockDim.x + threadIdx.x;
    int stride = gridDim.x * blockDim.x;
    for (; i < n; i += stride) out[i] = f2b(in[i]);
}

// ---------------- transpose + convert: in f32 [R][C] -> out bf16 [C][R] ----------------
__global__ void tr_cvt_kernel(const float* __restrict__ in, u16* __restrict__ out, int R, int C) {
    __shared__ float t[32][33];
    int bx = blockIdx.x * 32;  // C dim
    int by = blockIdx.y * 32;  // R dim
    int tx = threadIdx.x, ty = threadIdx.y;
#pragma unroll
    for (int k = 0; k < 32; k += 8) t[ty + k][tx] = in[(size_t)(by + ty + k) * C + bx + tx];
    __syncthreads();
#pragma unroll
    for (int k = 0; k < 32; k += 8) out[(size_t)(bx + ty + k) * R + by + tx] = f2b(t[tx][ty + k]);
}

// ---------------- GEMM: C[M,N] = A[M,K](bf16) * Bt[N,K](bf16)^T + bias ----------------
// EPI: 0 = f32 store, 1 = bf16 store, 2 = gelu + bf16 store
template <int EPI>
__global__ __launch_bounds__(256) void gemm_bt(const u16* __restrict__ A, const u16* __restrict__ Bt,
                                               const float* __restrict__ bias, void* __restrict__ Cout,
                                               int M, int N, int K) {
    __shared__ u16 lA[128 * 64];
    __shared__ u16 lB[128 * 64];
    const int tid = threadIdx.x;
    const int lane = tid & 63, wid = tid >> 6;
    const int wr = wid >> 1, wc = wid & 1;
    const int l15 = lane & 15, g4 = lane >> 4;
    const int bm = blockIdx.y, bn = blockIdx.x;

    const int arow = tid >> 3;          // 0..31
    const int acol = (tid & 7) * 8;
    const size_t abase = (size_t)(bm * 128) * K + acol;
    const size_t bbase = (size_t)(bn * 128) * K + acol;

    facc4 acc[4][4] = {};

    for (int k0 = 0; k0 < K; k0 += 64) {
        if (k0) __syncthreads();
#pragma unroll
        for (int i = 0; i < 4; i++) {
            gload_lds16(A + abase + (size_t)(i * 32 + arow) * K + k0, &lA[i * 2048 + tid * 8]);
            gload_lds16(Bt + bbase + (size_t)(i * 32 + arow) * K + k0, &lB[i * 2048 + tid * 8]);
        }
        __syncthreads();
#pragma unroll
        for (int kk = 0; kk < 64; kk += 32) {
            frag8 af[4], bf[4];
#pragma unroll
            for (int m = 0; m < 4; m++)
                af[m] = *(const frag8*)&lA[(wr * 64 + m * 16 + l15) * 64 + kk + g4 * 8];
#pragma unroll
            for (int n = 0; n < 4; n++)
                bf[n] = *(const frag8*)&lB[(wc * 64 + n * 16 + l15) * 64 + kk + g4 * 8];
#pragma unroll
            for (int m = 0; m < 4; m++)
#pragma unroll
                for (int n = 0; n < 4; n++)
                    acc[m][n] = __builtin_amdgcn_mfma_f32_16x16x32_bf16(af[m], bf[n], acc[m][n], 0, 0, 0);
        }
    }

    const int row0 = bm * 128 + wr * 64 + g4 * 4;
    const int col0 = bn * 128 + wc * 64 + l15;
#pragma unroll
    for (int n = 0; n < 4; n++) {
        const int col = col0 + n * 16;
        const float bv = bias[col];
#pragma unroll
        for (int m = 0; m < 4; m++) {
#pragma unroll
            for (int r = 0; r < 4; r++) {
                const int row = row0 + m * 16 + r;
                float v = acc[m][n][r] + bv;
                if (EPI == 2) v = gelu_exact(v);
                if (EPI == 0)
                    ((float*)Cout)[(size_t)row * N + col] = v;
                else
                    ((u16*)Cout)[(size_t)row * N + col] = f2b(v);
            }
        }
    }
}

// ---------------- flash attention: 1 wave per (16-row q-block, head) ----------------
// qkv bf16 [L][6144]; out bf16 [L][2048]; causal; scale 1/sqrt(D_MODEL)
__global__ __launch_bounds__(64) void attn_kernel(const u16* __restrict__ qkv, u16* __restrict__ out) {
    __shared__ u16 vt[128 * 40];  // V^T [d 0..127][key 0..31], padded row stride 40
    const int h = blockIdx.y, qb = blockIdx.x;
    const int q0 = qb * 16;
    const int lane = threadIdx.x;
    const int l15 = lane & 15, g4 = lane >> 4;
    const float scale = 0.022097086912079608f;  // 1/sqrt(2048)

    frag8 qf[4];
    {
        const u16* qrow = qkv + (size_t)(q0 + l15) * N_QKV + h * HEAD_D + g4 * 8;
#pragma unroll
        for (int c = 0; c < 4; c++) qf[c] = *(const frag8*)(qrow + c * 32);
    }

    float m_run = -1e30f, l_run = 0.0f;
    facc4 o[8] = {};

    const int nt = qb / 2 + 1;
    const int vkey = lane >> 1;        // 0..31
    const int vd0 = (lane & 1) * 64;   // 0 or 64

    for (int t = 0; t < nt; ++t) {
        const int kbase = t * 32;
        __syncthreads();
        {
            const u16* vrow = qkv + (size_t)(kbase + vkey) * N_QKV + 2 * D_MODEL + h * HEAD_D + vd0;
#pragma unroll
            for (int j = 0; j < 64; j++) vt[(vd0 + j) * 40 + vkey] = vrow[j];
        }
        __syncthreads();

        uint2 pb[2];
        pb[0].x = 0; pb[0].y = 0; pb[1].x = 0; pb[1].y = 0;
#pragma unroll
        for (int ks = 0; ks < 2; ++ks) {
            const int k0 = kbase + ks * 16;
            if (k0 <= q0 + 15) {
                facc4 s = {};
                const u16* krow = qkv + (size_t)(k0 + l15) * N_QKV + D_MODEL + h * HEAD_D + g4 * 8;
#pragma unroll
                for (int c = 0; c < 4; c++)
                    s = __builtin_amdgcn_mfma_f32_16x16x32_bf16(*(const frag8*)(krow + c * 32), qf[c], s, 0, 0, 0);
                // s[r]: key = k0 + g4*4 + r, q = q0 + l15
                float st[4];
                float mx = -1e30f;
#pragma unroll
                for (int r = 0; r < 4; r++) {
                    st[r] = s[r] * scale;
                    if (k0 + g4 * 4 + r > q0 + l15) st[r] = -1e30f;
                    mx = fmaxf(mx, st[r]);
                }
                mx = fmaxf(mx, __shfl_xor(mx, 16));
                mx = fmaxf(mx, __shfl_xor(mx, 32));
                const float m_new = fmaxf(m_run, mx);
                const float alpha = __expf(m_run - m_new);
                float ps = 0.0f;
                float p[4];
#pragma unroll
                for (int r = 0; r < 4; r++) { p[r] = __expf(st[r] - m_new); ps += p[r]; }
                ps += __shfl_xor(ps, 16);
                ps += __shfl_xor(ps, 32);
                l_run = l_run * alpha + ps;
                m_run = m_new;
#pragma unroll
                for (int c8 = 0; c8 < 8; c8++)
#pragma unroll
                    for (int r = 0; r < 4; r++) o[c8][r] *= alpha;
                pb[ks].x = (unsigned)f2b(p[0]) | ((unsigned)f2b(p[1]) << 16);
                pb[ks].y = (unsigned)f2b(p[2]) | ((unsigned)f2b(p[3]) << 16);
            }
        }

        // build P^T B-fragment: lane (g4,q=l15) needs keys 8*g4 .. 8*g4+7 (local)
        const int s0 = (2 * (g4 & 1)) * 16 + l15;
        const int s1 = s0 + 16;
        unsigned p00 = __shfl(pb[0].x, s0), p01 = __shfl(pb[0].y, s0);
        unsigned p02 = __shfl(pb[0].x, s1), p03 = __shfl(pb[0].y, s1);
        unsigned p10 = __shfl(pb[1].x, s0), p11 = __shfl(pb[1].y, s0);
        unsigned p12 = __shfl(pb[1].x, s1), p13 = __shfl(pb[1].y, s1);
        unsigned w[4];
        if (g4 < 2) { w[0] = p00; w[1] = p01; w[2] = p02; w[3] = p03; }
        else        { w[0] = p10; w[1] = p11; w[2] = p12; w[3] = p13; }
        frag8 pf = *(frag8*)w;

#pragma unroll
        for (int c8 = 0; c8 < 8; c8++) {
            frag8 vf = *(const frag8*)&vt[(c8 * 16 + l15) * 40 + g4 * 8];
            o[c8] = __builtin_amdgcn_mfma_f32_16x16x32_bf16(vf, pf, o[c8], 0, 0, 0);
        }
    }

    const float inv_l = 1.0f / l_run;
    u16* orow = out + (size_t)(q0 + l15) * D_MODEL + h * HEAD_D;
#pragma unroll
    for (int c8 = 0; c8 < 8; c8++)
#pragma unroll
        for (int r = 0; r < 4; r++)
            orow[c8 * 16 + g4 * 4 + r] = f2b(o[c8][r] * inv_l);
}

// ---------------- residual + layernorm (dual output f32 / bf16) ----------------
__global__ __launch_bounds__(256) void ln_kernel(const float* __restrict__ a, const float* __restrict__ b,
                                                 const float* __restrict__ gamma, const float* __restrict__ beta,
                                                 float* __restrict__ outf, u16* __restrict__ outb) {
    __shared__ float red[8];
    const int row = blockIdx.x;
    const int tid = threadIdx.x;
    const float* pa = a + (size_t)row * D_MODEL;
    const float* pb = b + (size_t)row * D_MODEL;
    float v[8];
    float s = 0.0f, s2 = 0.0f;
#pragma unroll
    for (int i = 0; i < 8; i++) {
        const int c = tid + i * 256;
        const float x = pa[c] + pb[c];
        v[i] = x;
        s += x;
        s2 += x * x;
    }
#pragma unroll
    for (int off = 32; off; off >>= 1) {
        s += __shfl_xor(s, off);
        s2 += __shfl_xor(s2, off);
    }
    if ((tid & 63) == 0) { red[(tid >> 6) * 2] = s; red[(tid >> 6) * 2 + 1] = s2; }
    __syncthreads();
    s = red[0] + red[2] + red[4] + red[6];
    s2 = red[1] + red[3] + red[5] + red[7];
    const float mean = s * (1.0f / D_MODEL);
    const float var = s2 * (1.0f / D_MODEL) - mean * mean;
    const float rstd = rsqrtf(var + 1e-5f);
#pragma unroll
    for (int i = 0; i < 8; i++) {
        const int c = tid + i * 256;
        const float y = (v[i] - mean) * rstd * gamma[c] + beta[c];
        if (outf) outf[(size_t)row * D_MODEL + c] = y;
        if (outb) outb[(size_t)row * D_MODEL + c] = f2b(y);
    }
}

extern "C" void kernel_launch(void* const* d_in, const int* in_sizes, int n_in,
                              void* d_out, int out_size, void* d_ws, size_t ws_size,
                              hipStream_t stream) {
    const float* x    = (const float*)d_in[0];
    const float* Wqkv = (const float*)d_in[1];
    const float* bqkv = (const float*)d_in[2];
    const float* Wo   = (const float*)d_in[3];
    const float* bo   = (const float*)d_in[4];
    const float* W1   = (const float*)d_in[5];
    const float* b1   = (const float*)d_in[6];
    const float* W2   = (const float*)d_in[7];
    const float* b2   = (const float*)d_in[8];
    const float* g1   = (const float*)d_in[9];
    const float* be1  = (const float*)d_in[10];
    const float* g2   = (const float*)d_in[11];
    const float* be2  = (const float*)d_in[12];

    char* ws = (char*)d_ws;
    const size_t MB = 1024 * 1024;
    // region plan (peak 120 MB, stream-ordered reuse):
    u16*  xb     = (u16*)(ws + 0);         // [0,8M)    x bf16
    u16*  WqkvT  = (u16*)(ws + 8 * MB);    // [8,32M)
    u16*  qkv    = (u16*)(ws + 32 * MB);   // [32,56M)
    u16*  attn_o = (u16*)(ws + 0);         // [0,8M)    reuses xb (dead)
    u16*  WoT    = (u16*)(ws + 8 * MB);    // [8,16M)   reuses WqkvT (dead)
    float* proj  = (float*)(ws + 16 * MB); // [16,32M)
    float* h     = (float*)(ws + 32 * MB); // [32,48M)  reuses qkv (dead)
    u16*  hb     = (u16*)(ws + 48 * MB);   // [48,56M)
    u16*  W1T    = (u16*)(ws + 56 * MB);   // [56,88M)
    u16*  f1     = (u16*)(ws + 88 * MB);   // [88,120M)
    u16*  W2T    = (u16*)(ws + 0);         // [0,32M)   reuses attn_o/WoT/proj (dead)
    float* f2    = (float*)(ws + 48 * MB); // [48,64M)  reuses hb/W1T head (dead)

    const dim3 b32(32, 8);

    // 1. x -> bf16
    cvt_bf16_kernel<<<2048, 256, 0, stream>>>(x, xb, L_SEQ * D_MODEL);
    // 2. Wqkv^T
    tr_cvt_kernel<<<dim3(N_QKV / 32, D_MODEL / 32), b32, 0, stream>>>(Wqkv, WqkvT, D_MODEL, N_QKV);
    // 3. qkv = x @ Wqkv + bqkv  (bf16 out)
    gemm_bt<1><<<dim3(N_QKV / 128, L_SEQ / 128), 256, 0, stream>>>(xb, WqkvT, bqkv, qkv, L_SEQ, N_QKV, D_MODEL);
    // 4. attention
    attn_kernel<<<dim3(L_SEQ / 16, N_HEADS), 64, 0, stream>>>(qkv, attn_o);
    // 5. Wo^T
    tr_cvt_kernel<<<dim3(D_MODEL / 32, D_MODEL / 32), b32, 0, stream>>>(Wo, WoT, D_MODEL, D_MODEL);
    // 6. proj = attn @ Wo + bo (f32 out)
    gemm_bt<0><<<dim3(D_MODEL / 128, L_SEQ / 128), 256, 0, stream>>>(attn_o, WoT, bo, proj, L_SEQ, D_MODEL, D_MODEL);
    // 7. h = LN(x + proj)*g1+be1  (f32 + bf16)
    ln_kernel<<<L_SEQ, 256, 0, stream>>>(x, proj, g1, be1, h, hb);
    // 8. W1^T
    tr_cvt_kernel<<<dim3(D_INNER / 32, D_MODEL / 32), b32, 0, stream>>>(W1, W1T, D_MODEL, D_INNER);
    // 9. f1 = gelu(h @ W1 + b1) (bf16)
    gemm_bt<2><<<dim3(D_INNER / 128, L_SEQ / 128), 256, 0, stream>>>(hb, W1T, b1, f1, L_SEQ, D_INNER, D_MODEL);
    // 10. W2^T
    tr_cvt_kernel<<<dim3(D_MODEL / 32, D_INNER / 32), b32, 0, stream>>>(W2, W2T, D_INNER, D_MODEL);
    // 11. f2 = f1 @ W2 + b2 (f32)
    gemm_bt<0><<<dim3(D_MODEL / 128, L_SEQ / 128), 256, 0, stream>>>(f1, W2T, b2, f2, L_SEQ, D_MODEL, D_INNER);
    // 12. out = LN(h + f2)*g2+be2
    ln_kernel<<<L_SEQ, 256, 0, stream>>>(h, f2, g2, be2, (float*)d_out, nullptr);
}

// Round 3
// 562.612 us; speedup vs baseline: 1.2445x; 1.2445x over previous
//
#include <hip/hip_runtime.h>
#include <hip/hip_bf16.h>

typedef unsigned short u16;
typedef __attribute__((ext_vector_type(8))) short frag8;   // 8 bf16
typedef __attribute__((ext_vector_type(4))) float facc4;   // 4 f32

#define L_SEQ 2048
#define D_MODEL 2048
#define N_HEADS 16
#define HEAD_D 128
#define N_QKV 6144
#define D_INNER 8192

__device__ __forceinline__ u16 f2b(float f) {
    __hip_bfloat16 h = __float2bfloat16(f);
    return *reinterpret_cast<u16*>(&h);
}

__device__ __forceinline__ void gload_lds16(const void* g, void* l) {
    __builtin_amdgcn_global_load_lds(
        (const __attribute__((address_space(1))) unsigned int*)g,
        (__attribute__((address_space(3))) unsigned int*)l, 16, 0, 0);
}

__device__ __forceinline__ float gelu_exact(float x) {
    return 0.5f * x * (1.0f + erff(x * 0.7071067811865475f));
}

// ---------------- elementwise f32 -> bf16 ----------------
__global__ void cvt_bf16_kernel(const float* __restrict__ in, u16* __restrict__ out, int n) {
    int i = blockIdx.x * blockDim.x + threadIdx.x;
    int stride = gridDim.x * blockDim.x;
    for (; i < n; i += stride) out[i] = f2b(in[i]);
}

// ---------------- transpose + convert: in f32 [R][C] -> out bf16 [C][R] ----------------
__global__ void tr_cvt_kernel(const float* __restrict__ in, u16* __restrict__ out, int R, int C) {
    __shared__ float t[32][33];
    int bx = blockIdx.x * 32;  // C dim
    int by = blockIdx.y * 32;  // R dim
    int tx = threadIdx.x, ty = threadIdx.y;
#pragma unroll
    for (int k = 0; k < 32; k += 8) t[ty + k][tx] = in[(size_t)(by + ty + k) * C + bx + tx];
    __syncthreads();
#pragma unroll
    for (int k = 0; k < 32; k += 8) out[(size_t)(bx + ty + k) * R + by + tx] = f2b(t[tx][ty + k]);
}

// ---------------- GEMM: C[M,N] = A[M,K](bf16) * Bt[N,K](bf16)^T + bias ----------------
// EPI: 0 = f32 store, 1 = bf16 store, 2 = gelu + bf16 store
template <int EPI>
__global__ __launch_bounds__(256) void gemm_bt(const u16* __restrict__ A, const u16* __restrict__ Bt,
                                               const float* __restrict__ bias, void* __restrict__ Cout,
                                               int M, int N, int K) {
    __shared__ u16 lA[128 * 64];
    __shared__ u16 lB[128 * 64];
    const int tid = threadIdx.x;
    const int lane = tid & 63, wid = tid >> 6;
    const int wr = wid >> 1, wc = wid & 1;
    const int l15 = lane & 15, g4 = lane >> 4;
    const int bm = blockIdx.y, bn = blockIdx.x;

    const int arow = tid >> 3;          // 0..31
    const int acol = (tid & 7) * 8;
    const size_t abase = (size_t)(bm * 128) * K + acol;
    const size_t bbase = (size_t)(bn * 128) * K + acol;

    facc4 acc[4][4] = {};

    for (int k0 = 0; k0 < K; k0 += 64) {
        if (k0) __syncthreads();
#pragma unroll
        for (int i = 0; i < 4; i++) {
            gload_lds16(A + abase + (size_t)(i * 32 + arow) * K + k0, &lA[i * 2048 + tid * 8]);
            gload_lds16(Bt + bbase + (size_t)(i * 32 + arow) * K + k0, &lB[i * 2048 + tid * 8]);
        }
        __syncthreads();
#pragma unroll
        for (int kk = 0; kk < 64; kk += 32) {
            frag8 af[4], bf[4];
#pragma unroll
            for (int m = 0; m < 4; m++)
                af[m] = *(const frag8*)&lA[(wr * 64 + m * 16 + l15) * 64 + kk + g4 * 8];
#pragma unroll
            for (int n = 0; n < 4; n++)
                bf[n] = *(const frag8*)&lB[(wc * 64 + n * 16 + l15) * 64 + kk + g4 * 8];
#pragma unroll
            for (int m = 0; m < 4; m++)
#pragma unroll
                for (int n = 0; n < 4; n++)
                    acc[m][n] = __builtin_amdgcn_mfma_f32_16x16x32_bf16(af[m], bf[n], acc[m][n], 0, 0, 0);
        }
    }

    const int row0 = bm * 128 + wr * 64 + g4 * 4;
    const int col0 = bn * 128 + wc * 64 + l15;
#pragma unroll
    for (int n = 0; n < 4; n++) {
        const int col = col0 + n * 16;
        const float bv = bias[col];
#pragma unroll
        for (int m = 0; m < 4; m++) {
#pragma unroll
            for (int r = 0; r < 4; r++) {
                const int row = row0 + m * 16 + r;
                float v = acc[m][n][r] + bv;
                if (EPI == 2) v = gelu_exact(v);
                if (EPI == 0)
                    ((float*)Cout)[(size_t)row * N + col] = v;
                else
                    ((u16*)Cout)[(size_t)row * N + col] = f2b(v);
            }
        }
    }
}

// ---------------- flash attention v3: 4 waves/block, 64 q-rows/block, KVBLK=64 ----------------
// qkv bf16 [L][6144]; out bf16 [L][2048]; causal; scale 1/sqrt(D_MODEL)
// LDS: K tile [64][128] XOR-swizzled row-major (staged with pre-swizzled global src, m201 pattern);
//      V tile stored transposed [d 0..127][key 0..63], row stride 72 u16 (144B, 16B-aligned),
//      staged via conflict-free scalar writes (lane = key -> consecutive LDS addresses).
__global__ __launch_bounds__(256) void attn_kernel(const u16* __restrict__ qkv, u16* __restrict__ out) {
    __shared__ u16 kT[64 * 128];
    __shared__ u16 vT[128 * 72];
    const int h = blockIdx.y;
    const int qb = (int)gridDim.x - 1 - (int)blockIdx.x;  // heavy blocks first
    const int tid = threadIdx.x;
    const int lane = tid & 63, w = tid >> 6;
    const int l15 = lane & 15, g4 = lane >> 4;
    const int q0 = qb * 64 + w * 16;
    const float scale = 0.022097086912079608f;  // 1/sqrt(2048)

    // Q fragments (held in registers for the whole kernel)
    frag8 qf[4];
    {
        const u16* qrow = qkv + (size_t)(q0 + l15) * N_QKV + h * HEAD_D + g4 * 8;
#pragma unroll
        for (int c = 0; c < 4; c++) qf[c] = *(const frag8*)(qrow + c * 32);
    }

    float m_run = -1e30f, l_run = 0.0f;
    facc4 o[8] = {};

    const int src0 = ((g4 & 1) << 5) + l15;  // source lane for P^T frag, elems 0..3
    const int src1 = src0 + 16;              // elems 4..7
    const bool hi = (g4 & 2) != 0;

    const int nt = qb + 1;
    for (int t = 0; t < nt; ++t) {
        const int kbase = t * 64;
        if (t) __syncthreads();
        // ---- cooperative staging ----
        const u16* kg_ptr = qkv + (size_t)kbase * N_QKV + D_MODEL + h * HEAD_D;
        const u16* vg_ptr = kg_ptr + D_MODEL;
        // V: lane loads key=lane, d in [w*32, w*32+32); issue loads early
        uint4 vv[4];
#pragma unroll
        for (int i = 0; i < 4; ++i)
            vv[i] = *(const uint4*)(vg_ptr + (size_t)lane * N_QKV + w * 32 + i * 8);
        // K: LDS row-major [row][256B], content pre-swizzled by ((row&7)<<4) bytes
#pragma unroll
        for (int p = 0; p < 4; ++p) {
            const int c = p * 256 + tid;
            const int row = c >> 4;
            const int colb = (c & 15) << 4;
            const int srcb = colb ^ ((row & 7) << 4);
            gload_lds16(kg_ptr + (size_t)row * N_QKV + (srcb >> 1), &kT[c * 8]);
        }
        // V transpose-write: step (i,e) -> row d = w*32+i*8+e, col = lane (conflict-free)
#pragma unroll
        for (int i = 0; i < 4; ++i) {
            const u16* pv = (const u16*)&vv[i];
#pragma unroll
            for (int e = 0; e < 8; ++e)
                vT[(w * 32 + i * 8 + e) * 72 + lane] = pv[e];
        }
        __syncthreads();

        const bool last = (t == nt - 1);

        // ---- QK^T (S^T = K * Q^T), batched over 4 16-key subtiles ----
        float st[16];
        float mx = -1e30f;
#pragma unroll
        for (int ks = 0; ks < 4; ++ks) {
            const bool active = !last || (ks <= w);
            if (active) {
                facc4 s = {};
                const int kl = ks * 16 + l15;
#pragma unroll
                for (int c = 0; c < 4; ++c) {
                    const int colb = (g4 * 16 + c * 64) ^ ((kl & 7) << 4);
                    frag8 kf = *(const frag8*)&kT[kl * 128 + (colb >> 1)];
                    s = __builtin_amdgcn_mfma_f32_16x16x32_bf16(kf, qf[c], s, 0, 0, 0);
                }
#pragma unroll
                for (int r = 0; r < 4; ++r) {
                    float v = s[r] * scale;
                    if (last) {
                        const int key = kbase + ks * 16 + g4 * 4 + r;
                        if (key > q0 + l15) v = -1e30f;
                    }
                    st[ks * 4 + r] = v;
                    mx = fmaxf(mx, v);
                }
            } else {
#pragma unroll
                for (int r = 0; r < 4; ++r) st[ks * 4 + r] = -1e30f;
            }
        }

        // ---- online softmax (one update per 64-key tile) ----
        mx = fmaxf(mx, __shfl_xor(mx, 16));
        mx = fmaxf(mx, __shfl_xor(mx, 32));
        const float m_new = fmaxf(m_run, mx);
        const float alpha = __expf(m_run - m_new);
        float ps = 0.0f;
        uint2 pb[4];
#pragma unroll
        for (int ks = 0; ks < 4; ++ks) {
            const float p0 = __expf(st[ks * 4 + 0] - m_new);
            const float p1 = __expf(st[ks * 4 + 1] - m_new);
            const float p2 = __expf(st[ks * 4 + 2] - m_new);
            const float p3 = __expf(st[ks * 4 + 3] - m_new);
            ps += (p0 + p1) + (p2 + p3);
            pb[ks].x = (unsigned)f2b(p0) | ((unsigned)f2b(p1) << 16);
            pb[ks].y = (unsigned)f2b(p2) | ((unsigned)f2b(p3) << 16);
        }
        ps += __shfl_xor(ps, 16);
        ps += __shfl_xor(ps, 32);
        l_run = l_run * alpha + ps;
        m_run = m_new;
#pragma unroll
        for (int c8 = 0; c8 < 8; ++c8)
#pragma unroll
            for (int r = 0; r < 4; ++r) o[c8][r] *= alpha;

        // ---- PV: O^T += V^T P^T over two 32-key phases ----
#pragma unroll
        for (int kp = 0; kp < 2; ++kp) {
            const bool kp_active = !last || (kp == 0) || (w >= 2);
            if (kp_active) {
                const uint2 a = pb[2 * kp], b = pb[2 * kp + 1];
                const unsigned a0 = __shfl(a.x, src0), a1 = __shfl(a.y, src0);
                const unsigned a2 = __shfl(a.x, src1), a3 = __shfl(a.y, src1);
                const unsigned b0 = __shfl(b.x, src0), b1 = __shfl(b.y, src0);
                const unsigned b2 = __shfl(b.x, src1), b3 = __shfl(b.y, src1);
                union { unsigned u[4]; frag8 f; } pu;
                pu.u[0] = hi ? b0 : a0;
                pu.u[1] = hi ? b1 : a1;
                pu.u[2] = hi ? b2 : a2;
                pu.u[3] = hi ? b3 : a3;
                const frag8 pf = pu.f;
#pragma unroll
                for (int c8 = 0; c8 < 8; ++c8) {
                    frag8 vf = *(const frag8*)&vT[(c8 * 16 + l15) * 72 + kp * 32 + g4 * 8];
                    o[c8] = __builtin_amdgcn_mfma_f32_16x16x32_bf16(vf, pf, o[c8], 0, 0, 0);
                }
            }
        }
    }

    const float inv_l = 1.0f / l_run;
    u16* orow = out + (size_t)(q0 + l15) * D_MODEL + h * HEAD_D;
#pragma unroll
    for (int c8 = 0; c8 < 8; ++c8) {
        uint2 st2;
        st2.x = (unsigned)f2b(o[c8][0] * inv_l) | ((unsigned)f2b(o[c8][1] * inv_l) << 16);
        st2.y = (unsigned)f2b(o[c8][2] * inv_l) | ((unsigned)f2b(o[c8][3] * inv_l) << 16);
        *(uint2*)&orow[c8 * 16 + g4 * 4] = st2;
    }
}

// ---------------- residual + layernorm (dual output f32 / bf16) ----------------
__global__ __launch_bounds__(256) void ln_kernel(const float* __restrict__ a, const float* __restrict__ b,
                                                 const float* __restrict__ gamma, const float* __restrict__ beta,
                                                 float* __restrict__ outf, u16* __restrict__ outb) {
    __shared__ float red[8];
    const int row = blockIdx.x;
    const int tid = threadIdx.x;
    const float* pa = a + (size_t)row * D_MODEL;
    const float* pb = b + (size_t)row * D_MODEL;
    float v[8];
    float s = 0.0f, s2 = 0.0f;
#pragma unroll
    for (int i = 0; i < 8; i++) {
        const int c = tid + i * 256;
        const float x = pa[c] + pb[c];
        v[i] = x;
        s += x;
        s2 += x * x;
    }
#pragma unroll
    for (int off = 32; off; off >>= 1) {
        s += __shfl_xor(s, off);
        s2 += __shfl_xor(s2, off);
    }
    if ((tid & 63) == 0) { red[(tid >> 6) * 2] = s; red[(tid >> 6) * 2 + 1] = s2; }
    __syncthreads();
    s = red[0] + red[2] + red[4] + red[6];
    s2 = red[1] + red[3] + red[5] + red[7];
    const float mean = s * (1.0f / D_MODEL);
    const float var = s2 * (1.0f / D_MODEL) - mean * mean;
    const float rstd = rsqrtf(var + 1e-5f);
#pragma unroll
    for (int i = 0; i < 8; i++) {
        const int c = tid + i * 256;
        const float y = (v[i] - mean) * rstd * gamma[c] + beta[c];
        if (outf) outf[(size_t)row * D_MODEL + c] = y;
        if (outb) outb[(size_t)row * D_MODEL + c] = f2b(y);
    }
}

extern "C" void kernel_launch(void* const* d_in, const int* in_sizes, int n_in,
                              void* d_out, int out_size, void* d_ws, size_t ws_size,
                              hipStream_t stream) {
    const float* x    = (const float*)d_in[0];
    const float* Wqkv = (const float*)d_in[1];
    const float* bqkv = (const float*)d_in[2];
    const float* Wo   = (const float*)d_in[3];
    const float* bo   = (const float*)d_in[4];
    const float* W1   = (const float*)d_in[5];
    const float* b1   = (const float*)d_in[6];
    const float* W2   = (const float*)d_in[7];
    const float* b2   = (const float*)d_in[8];
    const float* g1   = (const float*)d_in[9];
    const float* be1  = (const float*)d_in[10];
    const float* g2   = (const float*)d_in[11];
    const float* be2  = (const float*)d_in[12];

    char* ws = (char*)d_ws;
    const size_t MB = 1024 * 1024;
    // region plan (peak 120 MB, stream-ordered reuse):
    u16*  xb     = (u16*)(ws + 0);         // [0,8M)    x bf16
    u16*  WqkvT  = (u16*)(ws + 8 * MB);    // [8,32M)
    u16*  qkv    = (u16*)(ws + 32 * MB);   // [32,56M)
    u16*  attn_o = (u16*)(ws + 0);         // [0,8M)    reuses xb (dead)
    u16*  WoT    = (u16*)(ws + 8 * MB);    // [8,16M)   reuses WqkvT (dead)
    float* proj  = (float*)(ws + 16 * MB); // [16,32M)
    float* h     = (float*)(ws + 32 * MB); // [32,48M)  reuses qkv (dead)
    u16*  hb     = (u16*)(ws + 48 * MB);   // [48,56M)
    u16*  W1T    = (u16*)(ws + 56 * MB);   // [56,88M)
    u16*  f1     = (u16*)(ws + 88 * MB);   // [88,120M)
    u16*  W2T    = (u16*)(ws + 0);         // [0,32M)   reuses attn_o/WoT/proj (dead)
    float* f2    = (float*)(ws + 48 * MB); // [48,64M)  reuses hb/W1T head (dead)

    const dim3 b32(32, 8);

    // 1. x -> bf16
    cvt_bf16_kernel<<<2048, 256, 0, stream>>>(x, xb, L_SEQ * D_MODEL);
    // 2. Wqkv^T
    tr_cvt_kernel<<<dim3(N_QKV / 32, D_MODEL / 32), b32, 0, stream>>>(Wqkv, WqkvT, D_MODEL, N_QKV);
    // 3. qkv = x @ Wqkv + bqkv  (bf16 out)
    gemm_bt<1><<<dim3(N_QKV / 128, L_SEQ / 128), 256, 0, stream>>>(xb, WqkvT, bqkv, qkv, L_SEQ, N_QKV, D_MODEL);
    // 4. attention (4 waves/block, 64 q-rows/block)
    attn_kernel<<<dim3(L_SEQ / 64, N_HEADS), 256, 0, stream>>>(qkv, attn_o);
    // 5. Wo^T
    tr_cvt_kernel<<<dim3(D_MODEL / 32, D_MODEL / 32), b32, 0, stream>>>(Wo, WoT, D_MODEL, D_MODEL);
    // 6. proj = attn @ Wo + bo (f32 out)
    gemm_bt<0><<<dim3(D_MODEL / 128, L_SEQ / 128), 256, 0, stream>>>(attn_o, WoT, bo, proj, L_SEQ, D_MODEL, D_MODEL);
    // 7. h = LN(x + proj)*g1+be1  (f32 + bf16)
    ln_kernel<<<L_SEQ, 256, 0, stream>>>(x, proj, g1, be1, h, hb);
    // 8. W1^T
    tr_cvt_kernel<<<dim3(D_INNER / 32, D_MODEL / 32), b32, 0, stream>>>(W1, W1T, D_MODEL, D_INNER);
    // 9. f1 = gelu(h @ W1 + b1) (bf16)
    gemm_bt<2><<<dim3(D_INNER / 128, L_SEQ / 128), 256, 0, stream>>>(hb, W1T, b1, f1, L_SEQ, D_INNER, D_MODEL);
    // 10. W2^T
    tr_cvt_kernel<<<dim3(D_MODEL / 32, D_INNER / 32), b32, 0, stream>>>(W2, W2T, D_INNER, D_MODEL);
    // 11. f2 = f1 @ W2 + b2 (f32)
    gemm_bt<0><<<dim3(D_MODEL / 128, L_SEQ / 128), 256, 0, stream>>>(f1, W2T, b2, f2, L_SEQ, D_MODEL, D_INNER);
    // 12. out = LN(h + f2)*g2+be2
    ln_kernel<<<L_SEQ, 256, 0, stream>>>(h, f2, g2, be2, (float*)d_out, nullptr);
}

// Round 4
// 512.594 us; speedup vs baseline: 1.3659x; 1.0976x over previous
//
#include <hip/hip_runtime.h>
#include <hip/hip_bf16.h>

typedef unsigned short u16;
typedef __attribute__((ext_vector_type(8))) short frag8;   // 8 bf16
typedef __attribute__((ext_vector_type(4))) float facc4;   // 4 f32

#define L_SEQ 2048
#define D_MODEL 2048
#define N_HEADS 16
#define HEAD_D 128
#define N_QKV 6144
#define D_INNER 8192

__device__ __forceinline__ u16 f2b(float f) {
    __hip_bfloat16 h = __float2bfloat16(f);
    return *reinterpret_cast<u16*>(&h);
}

__device__ __forceinline__ void gload_lds16(const void* g, void* l) {
    __builtin_amdgcn_global_load_lds(
        (const __attribute__((address_space(1))) unsigned int*)g,
        (__attribute__((address_space(3))) unsigned int*)l, 16, 0, 0);
}

__device__ __forceinline__ float gelu_exact(float x) {
    return 0.5f * x * (1.0f + erff(x * 0.7071067811865475f));
}

// ---------------- elementwise f32 -> bf16 ----------------
__global__ void cvt_bf16_kernel(const float* __restrict__ in, u16* __restrict__ out, int n) {
    int i = blockIdx.x * blockDim.x + threadIdx.x;
    int stride = gridDim.x * blockDim.x;
    for (; i < n; i += stride) out[i] = f2b(in[i]);
}

// ---------------- transpose + convert: in f32 [R][C] -> out bf16 [C][R] ----------------
__global__ void tr_cvt_kernel(const float* __restrict__ in, u16* __restrict__ out, int R, int C) {
    __shared__ float t[32][33];
    int bx = blockIdx.x * 32;  // C dim
    int by = blockIdx.y * 32;  // R dim
    int tx = threadIdx.x, ty = threadIdx.y;
#pragma unroll
    for (int k = 0; k < 32; k += 8) t[ty + k][tx] = in[(size_t)(by + ty + k) * C + bx + tx];
    __syncthreads();
#pragma unroll
    for (int k = 0; k < 32; k += 8) out[(size_t)(bx + ty + k) * R + by + tx] = f2b(t[tx][ty + k]);
}

// ---------------- legacy 128x128 GEMM (kept for proj) ----------------
template <int EPI>  // 0 = f32+bias
__global__ __launch_bounds__(256) void gemm_bt(const u16* __restrict__ A, const u16* __restrict__ Bt,
                                               const float* __restrict__ bias, void* __restrict__ Cout,
                                               int M, int N, int K) {
    __shared__ u16 lA[128 * 64];
    __shared__ u16 lB[128 * 64];
    const int tid = threadIdx.x;
    const int lane = tid & 63, wid = tid >> 6;
    const int wr = wid >> 1, wc = wid & 1;
    const int l15 = lane & 15, g4 = lane >> 4;
    const int bm = blockIdx.y, bn = blockIdx.x;

    const int arow = tid >> 3;
    const int acol = (tid & 7) * 8;
    const size_t abase = (size_t)(bm * 128) * K + acol;
    const size_t bbase = (size_t)(bn * 128) * K + acol;

    facc4 acc[4][4] = {};

    for (int k0 = 0; k0 < K; k0 += 64) {
        if (k0) __syncthreads();
#pragma unroll
        for (int i = 0; i < 4; i++) {
            gload_lds16(A + abase + (size_t)(i * 32 + arow) * K + k0, &lA[i * 2048 + tid * 8]);
            gload_lds16(Bt + bbase + (size_t)(i * 32 + arow) * K + k0, &lB[i * 2048 + tid * 8]);
        }
        __syncthreads();
#pragma unroll
        for (int kk = 0; kk < 64; kk += 32) {
            frag8 af[4], bf[4];
#pragma unroll
            for (int m = 0; m < 4; m++)
                af[m] = *(const frag8*)&lA[(wr * 64 + m * 16 + l15) * 64 + kk + g4 * 8];
#pragma unroll
            for (int n = 0; n < 4; n++)
                bf[n] = *(const frag8*)&lB[(wc * 64 + n * 16 + l15) * 64 + kk + g4 * 8];
#pragma unroll
            for (int m = 0; m < 4; m++)
#pragma unroll
                for (int n = 0; n < 4; n++)
                    acc[m][n] = __builtin_amdgcn_mfma_f32_16x16x32_bf16(af[m], bf[n], acc[m][n], 0, 0, 0);
        }
    }

    const int row0 = bm * 128 + wr * 64 + g4 * 4;
    const int col0 = bn * 128 + wc * 64 + l15;
#pragma unroll
    for (int n = 0; n < 4; n++) {
        const int col = col0 + n * 16;
        const float bv = bias[col];
#pragma unroll
        for (int m = 0; m < 4; m++) {
#pragma unroll
            for (int r = 0; r < 4; r++) {
                const int row = row0 + m * 16 + r;
                float v = acc[m][n][r] + bv;
                ((float*)Cout)[(size_t)row * N + col] = v;
            }
        }
    }
}

// ---------------- gemm256: 256x256 tile, BK=32, ring-4 LDS pipeline, counted vmcnt ----------------
// C[M,N] = A[M,K](bf16) * Bt[N,K](bf16)^T.  8 waves (2M x 4N), per-wave 128x64 output.
// LDS ring: 4 stages x (A 256x32 + B 256x32) bf16 = 128 KiB, XOR-swizzled
// (chunk16B ^= ((row>>1)&3)<<4, involution; staged pre-swizzled via global src).
// EPI: 0 f32+bias, 1 bf16+bias, 2 gelu+bf16+bias, 3 f32 partial (no bias, plane per blockIdx.z)
template <int EPI>
__global__ __launch_bounds__(512, 2) void gemm256(const u16* __restrict__ A, const u16* __restrict__ Bt,
                                                  const float* __restrict__ bias, void* __restrict__ Cout,
                                                  int M, int N, int K, int kseg, int nbn) {
    __shared__ u16 lds[4 * 16384];  // stage s: A at s*16384, B at s*16384+8192 (u16 units)
    const int tid = threadIdx.x;
    const int lane = tid & 63, wid = tid >> 6;
    const int wm = wid >> 2, wn = wid & 3;
    const int l15 = lane & 15, g4 = lane >> 4;

    // XCD-chunked block swizzle (all grids used have nwg % 8 == 0)
    const int nwg = gridDim.x;
    const int q8 = nwg >> 3;
    const int wg = (blockIdx.x & 7) * q8 + (blockIdx.x >> 3);
    const int bn = wg % nbn, bm = wg / nbn;
    const int kb = blockIdx.z * kseg;
    const int nt = kseg >> 5;

    // staging constants: thread covers row rA (+0/128), 16B chunk (tid&3), source pre-swizzled
    const int rA = tid >> 2;
    const int swzT = ((tid >> 3) & 3) << 4;                 // ((rA>>1)&3)<<4  (bytes)
    const int srcE = ((((tid & 3) << 4) ^ swzT) >> 1);      // source elem offset in 32-elem row
    const u16* Ab = A + (size_t)(bm * 256 + rA) * K + kb + srcE;
    const u16* Bb = Bt + (size_t)(bn * 256 + rA) * K + kb + srcE;
    const size_t rstride = (size_t)128 * K;

    // fragment read offsets (u16 units), swizzle applied
    int aoff[8], boff[4];
#pragma unroll
    for (int mf = 0; mf < 8; mf++) {
        const int rowl = wm * 128 + mf * 16 + l15;
        aoff[mf] = rowl * 32 + (((g4 * 16) ^ (((rowl >> 1) & 3) << 4)) >> 1);
    }
#pragma unroll
    for (int nf = 0; nf < 4; nf++) {
        const int rowl = wn * 64 + nf * 16 + l15;
        boff[nf] = rowl * 32 + (((g4 * 16) ^ (((rowl >> 1) & 3) << 4)) >> 1);
    }

    auto stageA = [&](int tt) {
        u16* sA = &lds[(tt & 3) * 16384];
        const u16* g = Ab + (size_t)tt * 32;
        gload_lds16(g, sA + tid * 8);
        gload_lds16(g + rstride, sA + 4096 + tid * 8);
    };
    auto stageB = [&](int tt) {
        u16* sB = &lds[(tt & 3) * 16384 + 8192];
        const u16* g = Bb + (size_t)tt * 32;
        gload_lds16(g, sB + tid * 8);
        gload_lds16(g + rstride, sB + 4096 + tid * 8);
    };

    facc4 acc[8][4] = {};

    // prologue: stage tiles 0,1,2; wait stage 0 complete (8 newest stay in flight)
    stageA(0); stageB(0);
    stageA(1); stageB(1);
    stageA(2); stageB(2);
    asm volatile("s_waitcnt vmcnt(8)" ::: "memory");
    __builtin_amdgcn_s_barrier();
    __builtin_amdgcn_sched_barrier(0);

    for (int t = 0; t < nt; ++t) {
        const u16* sA = &lds[(t & 3) * 16384];
        const u16* sB = sA + 8192;
        // ---- phase 0: m-frags 0..3 ----
        frag8 a0[4], b0[4];
#pragma unroll
        for (int i = 0; i < 4; i++) a0[i] = *(const frag8*)&sA[aoff[i]];
#pragma unroll
        for (int i = 0; i < 4; i++) b0[i] = *(const frag8*)&sB[boff[i]];
        if (t + 3 < nt) stageA(t + 3);
        __builtin_amdgcn_s_setprio(1);
#pragma unroll
        for (int mf = 0; mf < 4; mf++)
#pragma unroll
            for (int nf = 0; nf < 4; nf++)
                acc[mf][nf] = __builtin_amdgcn_mfma_f32_16x16x32_bf16(a0[mf], b0[nf], acc[mf][nf], 0, 0, 0);
        __builtin_amdgcn_s_setprio(0);
        __builtin_amdgcn_s_barrier();
        // ---- phase 1: m-frags 4..7 ----
        frag8 a1[4];
#pragma unroll
        for (int i = 0; i < 4; i++) a1[i] = *(const frag8*)&sA[aoff[4 + i]];
        if (t + 3 < nt) stageB(t + 3);
        __builtin_amdgcn_s_setprio(1);
#pragma unroll
        for (int mf = 0; mf < 4; mf++)
#pragma unroll
            for (int nf = 0; nf < 4; nf++)
                acc[4 + mf][nf] = __builtin_amdgcn_mfma_f32_16x16x32_bf16(a1[mf], b0[nf], acc[4 + mf][nf], 0, 0, 0);
        __builtin_amdgcn_s_setprio(0);
        // ---- tile boundary: derived wait (next tile complete; newest prefetches stay in flight) ----
        if (t + 3 < nt)
            asm volatile("s_waitcnt vmcnt(8)" ::: "memory");
        else if (t + 2 < nt)
            asm volatile("s_waitcnt vmcnt(4)" ::: "memory");
        else
            asm volatile("s_waitcnt vmcnt(0)" ::: "memory");
        __builtin_amdgcn_s_barrier();
        __builtin_amdgcn_sched_barrier(0);
    }

    // ---- epilogue ----
    const int row0 = bm * 256 + wm * 128 + g4 * 4;
    const int col0 = bn * 256 + wn * 64 + l15;
    float* fout = (EPI == 3) ? ((float*)Cout + (size_t)blockIdx.z * M * N) : (float*)Cout;
#pragma unroll
    for (int nf = 0; nf < 4; nf++) {
        const int col = col0 + nf * 16;
        const float bv = (EPI == 3) ? 0.0f : bias[col];
#pragma unroll
        for (int mf = 0; mf < 8; mf++) {
#pragma unroll
            for (int r = 0; r < 4; r++) {
                const int row = row0 + mf * 16 + r;
                float v = acc[mf][nf][r] + bv;
                if (EPI == 2) v = gelu_exact(v);
                if (EPI == 0 || EPI == 3)
                    fout[(size_t)row * N + col] = v;
                else
                    ((u16*)Cout)[(size_t)row * N + col] = f2b(v);
            }
        }
    }
}

// ---------------- flash attention: 4 waves/block, 64 q-rows/block, KVBLK=64 ----------------
__global__ __launch_bounds__(256) void attn_kernel(const u16* __restrict__ qkv, u16* __restrict__ out) {
    __shared__ u16 kT[64 * 128];
    __shared__ u16 vT[128 * 72];
    const int h = blockIdx.y;
    const int qb = (int)gridDim.x - 1 - (int)blockIdx.x;  // heavy blocks first
    const int tid = threadIdx.x;
    const int lane = tid & 63, w = tid >> 6;
    const int l15 = lane & 15, g4 = lane >> 4;
    const int q0 = qb * 64 + w * 16;
    const float scale = 0.022097086912079608f;  // 1/sqrt(2048)

    frag8 qf[4];
    {
        const u16* qrow = qkv + (size_t)(q0 + l15) * N_QKV + h * HEAD_D + g4 * 8;
#pragma unroll
        for (int c = 0; c < 4; c++) qf[c] = *(const frag8*)(qrow + c * 32);
    }

    float m_run = -1e30f, l_run = 0.0f;
    facc4 o[8] = {};

    const int src0 = ((g4 & 1) << 5) + l15;
    const int src1 = src0 + 16;
    const bool hi = (g4 & 2) != 0;

    const int nt = qb + 1;
    for (int t = 0; t < nt; ++t) {
        const int kbase = t * 64;
        if (t) __syncthreads();
        const u16* kg_ptr = qkv + (size_t)kbase * N_QKV + D_MODEL + h * HEAD_D;
        const u16* vg_ptr = kg_ptr + D_MODEL;
        uint4 vv[4];
#pragma unroll
        for (int i = 0; i < 4; ++i)
            vv[i] = *(const uint4*)(vg_ptr + (size_t)lane * N_QKV + w * 32 + i * 8);
#pragma unroll
        for (int p = 0; p < 4; ++p) {
            const int c = p * 256 + tid;
            const int row = c >> 4;
            const int colb = (c & 15) << 4;
            const int srcb = colb ^ ((row & 7) << 4);
            gload_lds16(kg_ptr + (size_t)row * N_QKV + (srcb >> 1), &kT[c * 8]);
        }
#pragma unroll
        for (int i = 0; i < 4; ++i) {
            const u16* pv = (const u16*)&vv[i];
#pragma unroll
            for (int e = 0; e < 8; ++e)
                vT[(w * 32 + i * 8 + e) * 72 + lane] = pv[e];
        }
        __syncthreads();

        const bool last = (t == nt - 1);

        float st[16];
        float mx = -1e30f;
#pragma unroll
        for (int ks = 0; ks < 4; ++ks) {
            const bool active = !last || (ks <= w);
            if (active) {
                facc4 s = {};
                const int kl = ks * 16 + l15;
#pragma unroll
                for (int c = 0; c < 4; ++c) {
                    const int colb = (g4 * 16 + c * 64) ^ ((kl & 7) << 4);
                    frag8 kf = *(const frag8*)&kT[kl * 128 + (colb >> 1)];
                    s = __builtin_amdgcn_mfma_f32_16x16x32_bf16(kf, qf[c], s, 0, 0, 0);
                }
#pragma unroll
                for (int r = 0; r < 4; ++r) {
                    float v = s[r] * scale;
                    if (last) {
                        const int key = kbase + ks * 16 + g4 * 4 + r;
                        if (key > q0 + l15) v = -1e30f;
                    }
                    st[ks * 4 + r] = v;
                    mx = fmaxf(mx, v);
                }
            } else {
#pragma unroll
                for (int r = 0; r < 4; ++r) st[ks * 4 + r] = -1e30f;
            }
        }

        mx = fmaxf(mx, __shfl_xor(mx, 16));
        mx = fmaxf(mx, __shfl_xor(mx, 32));
        const float m_new = fmaxf(m_run, mx);
        const float alpha = __expf(m_run - m_new);
        float ps = 0.0f;
        uint2 pb[4];
#pragma unroll
        for (int ks = 0; ks < 4; ++ks) {
            const float p0 = __expf(st[ks * 4 + 0] - m_new);
            const float p1 = __expf(st[ks * 4 + 1] - m_new);
            const float p2 = __expf(st[ks * 4 + 2] - m_new);
            const float p3 = __expf(st[ks * 4 + 3] - m_new);
            ps += (p0 + p1) + (p2 + p3);
            pb[ks].x = (unsigned)f2b(p0) | ((unsigned)f2b(p1) << 16);
            pb[ks].y = (unsigned)f2b(p2) | ((unsigned)f2b(p3) << 16);
        }
        ps += __shfl_xor(ps, 16);
        ps += __shfl_xor(ps, 32);
        l_run = l_run * alpha + ps;
        m_run = m_new;
#pragma unroll
        for (int c8 = 0; c8 < 8; ++c8)
#pragma unroll
            for (int r = 0; r < 4; ++r) o[c8][r] *= alpha;

#pragma unroll
        for (int kp = 0; kp < 2; ++kp) {
            const bool kp_active = !last || (kp == 0) || (w >= 2);
            if (kp_active) {
                const uint2 a = pb[2 * kp], b = pb[2 * kp + 1];
                const unsigned a0 = __shfl(a.x, src0), a1 = __shfl(a.y, src0);
                const unsigned a2 = __shfl(a.x, src1), a3 = __shfl(a.y, src1);
                const unsigned b0 = __shfl(b.x, src0), b1 = __shfl(b.y, src0);
                const unsigned b2 = __shfl(b.x, src1), b3 = __shfl(b.y, src1);
                union { unsigned u[4]; frag8 f; } pu;
                pu.u[0] = hi ? b0 : a0;
                pu.u[1] = hi ? b1 : a1;
                pu.u[2] = hi ? b2 : a2;
                pu.u[3] = hi ? b3 : a3;
                const frag8 pf = pu.f;
#pragma unroll
                for (int c8 = 0; c8 < 8; ++c8) {
                    frag8 vf = *(const frag8*)&vT[(c8 * 16 + l15) * 72 + kp * 32 + g4 * 8];
                    o[c8] = __builtin_amdgcn_mfma_f32_16x16x32_bf16(vf, pf, o[c8], 0, 0, 0);
                }
            }
        }
    }

    const float inv_l = 1.0f / l_run;
    u16* orow = out + (size_t)(q0 + l15) * D_MODEL + h * HEAD_D;
#pragma unroll
    for (int c8 = 0; c8 < 8; ++c8) {
        uint2 st2;
        st2.x = (unsigned)f2b(o[c8][0] * inv_l) | ((unsigned)f2b(o[c8][1] * inv_l) << 16);
        st2.y = (unsigned)f2b(o[c8][2] * inv_l) | ((unsigned)f2b(o[c8][3] * inv_l) << 16);
        *(uint2*)&orow[c8 * 16 + g4 * 4] = st2;
    }
}

// ---------------- residual + layernorm (dual output f32 / bf16) ----------------
__global__ __launch_bounds__(256) void ln_kernel(const float* __restrict__ a, const float* __restrict__ b,
                                                 const float* __restrict__ gamma, const float* __restrict__ beta,
                                                 float* __restrict__ outf, u16* __restrict__ outb) {
    __shared__ float red[8];
    const int row = blockIdx.x;
    const int tid = threadIdx.x;
    const float* pa = a + (size_t)row * D_MODEL;
    const float* pb = b + (size_t)row * D_MODEL;
    float v[8];
    float s = 0.0f, s2 = 0.0f;
#pragma unroll
    for (int i = 0; i < 8; i++) {
        const int c = tid + i * 256;
        const float x = pa[c] + pb[c];
        v[i] = x;
        s += x;
        s2 += x * x;
    }
#pragma unroll
    for (int off = 32; off; off >>= 1) {
        s += __shfl_xor(s, off);
        s2 += __shfl_xor(s2, off);
    }
    if ((tid & 63) == 0) { red[(tid >> 6) * 2] = s; red[(tid >> 6) * 2 + 1] = s2; }
    __syncthreads();
    s = red[0] + red[2] + red[4] + red[6];
    s2 = red[1] + red[3] + red[5] + red[7];
    const float mean = s * (1.0f / D_MODEL);
    const float var = s2 * (1.0f / D_MODEL) - mean * mean;
    const float rstd = rsqrtf(var + 1e-5f);
#pragma unroll
    for (int i = 0; i < 8; i++) {
        const int c = tid + i * 256;
        const float y = (v[i] - mean) * rstd * gamma[c] + beta[c];
        if (outf) outf[(size_t)row * D_MODEL + c] = y;
        if (outb) outb[(size_t)row * D_MODEL + c] = f2b(y);
    }
}

// ---------------- residual + Σ split-K partials + bias + layernorm ----------------
__global__ __launch_bounds__(256) void ln_part_kernel(const float* __restrict__ a, const float* __restrict__ parts,
                                                      int np, const float* __restrict__ bias,
                                                      const float* __restrict__ gamma, const float* __restrict__ beta,
                                                      float* __restrict__ outf) {
    __shared__ float red[8];
    const int row = blockIdx.x;
    const int tid = threadIdx.x;
    const size_t plane = (size_t)L_SEQ * D_MODEL;
    const float* pa = a + (size_t)row * D_MODEL;
    float v[8];
    float s = 0.0f, s2 = 0.0f;
#pragma unroll
    for (int i = 0; i < 8; i++) {
        const int c = tid + i * 256;
        float x = pa[c] + bias[c];
        for (int p = 0; p < np; ++p) x += parts[p * plane + (size_t)row * D_MODEL + c];
        v[i] = x;
        s += x;
        s2 += x * x;
    }
#pragma unroll
    for (int off = 32; off; off >>= 1) {
        s += __shfl_xor(s, off);
        s2 += __shfl_xor(s2, off);
    }
    if ((tid & 63) == 0) { red[(tid >> 6) * 2] = s; red[(tid >> 6) * 2 + 1] = s2; }
    __syncthreads();
    s = red[0] + red[2] + red[4] + red[6];
    s2 = red[1] + red[3] + red[5] + red[7];
    const float mean = s * (1.0f / D_MODEL);
    const float var = s2 * (1.0f / D_MODEL) - mean * mean;
    const float rstd = rsqrtf(var + 1e-5f);
#pragma unroll
    for (int i = 0; i < 8; i++) {
        const int c = tid + i * 256;
        outf[(size_t)row * D_MODEL + c] = (v[i] - mean) * rstd * gamma[c] + beta[c];
    }
}

extern "C" void kernel_launch(void* const* d_in, const int* in_sizes, int n_in,
                              void* d_out, int out_size, void* d_ws, size_t ws_size,
                              hipStream_t stream) {
    const float* x    = (const float*)d_in[0];
    const float* Wqkv = (const float*)d_in[1];
    const float* bqkv = (const float*)d_in[2];
    const float* Wo   = (const float*)d_in[3];
    const float* bo   = (const float*)d_in[4];
    const float* W1   = (const float*)d_in[5];
    const float* b1   = (const float*)d_in[6];
    const float* W2   = (const float*)d_in[7];
    const float* b2   = (const float*)d_in[8];
    const float* g1   = (const float*)d_in[9];
    const float* be1  = (const float*)d_in[10];
    const float* g2   = (const float*)d_in[11];
    const float* be2  = (const float*)d_in[12];

    char* ws = (char*)d_ws;
    const size_t MB = 1024 * 1024;
    // region plan (peak 120 MB, stream-ordered reuse):
    u16*  xb     = (u16*)(ws + 0);         // [0,8M)
    u16*  WqkvT  = (u16*)(ws + 8 * MB);    // [8,32M)
    u16*  qkv    = (u16*)(ws + 32 * MB);   // [32,56M)
    u16*  attn_o = (u16*)(ws + 0);         // [0,8M)   reuses xb
    u16*  WoT    = (u16*)(ws + 8 * MB);    // [8,16M)  reuses WqkvT
    float* proj  = (float*)(ws + 16 * MB); // [16,32M)
    float* h     = (float*)(ws + 32 * MB); // [32,48M) reuses qkv
    u16*  hb     = (u16*)(ws + 48 * MB);   // [48,56M)
    u16*  W1T    = (u16*)(ws + 56 * MB);   // [56,88M)
    u16*  f1     = (u16*)(ws + 88 * MB);   // [88,120M)
    u16*  W2T    = (u16*)(ws + 0);         // [0,32M)  reuses attn_o/WoT/proj
    float* parts = (float*)(ws + 48 * MB); // [48,80M) reuses hb + W1T head (2 planes x 16MB)

    const dim3 b32(32, 8);

    // 1. x -> bf16
    cvt_bf16_kernel<<<2048, 256, 0, stream>>>(x, xb, L_SEQ * D_MODEL);
    // 2. Wqkv^T
    tr_cvt_kernel<<<dim3(N_QKV / 32, D_MODEL / 32), b32, 0, stream>>>(Wqkv, WqkvT, D_MODEL, N_QKV);
    // 3. qkv = x @ Wqkv + bqkv  (bf16 out)  grid 24x8 = 192 blocks
    gemm256<1><<<dim3(192, 1, 1), 512, 0, stream>>>(xb, WqkvT, bqkv, qkv, L_SEQ, N_QKV, D_MODEL, D_MODEL, 24);
    // 4. attention
    attn_kernel<<<dim3(L_SEQ / 64, N_HEADS), 256, 0, stream>>>(qkv, attn_o);
    // 5. Wo^T
    tr_cvt_kernel<<<dim3(D_MODEL / 32, D_MODEL / 32), b32, 0, stream>>>(Wo, WoT, D_MODEL, D_MODEL);
    // 6. proj = attn @ Wo + bo (f32 out) — legacy 128x128 (256 blocks, good occupancy)
    gemm_bt<0><<<dim3(D_MODEL / 128, L_SEQ / 128), 256, 0, stream>>>(attn_o, WoT, bo, proj, L_SEQ, D_MODEL, D_MODEL);
    // 7. h = LN(x + proj)*g1+be1  (f32 + bf16)
    ln_kernel<<<L_SEQ, 256, 0, stream>>>(x, proj, g1, be1, h, hb);
    // 8. W1^T
    tr_cvt_kernel<<<dim3(D_INNER / 32, D_MODEL / 32), b32, 0, stream>>>(W1, W1T, D_MODEL, D_INNER);
    // 9. f1 = gelu(h @ W1 + b1) (bf16)  grid 32x8 = 256 blocks
    gemm256<2><<<dim3(256, 1, 1), 512, 0, stream>>>(hb, W1T, b1, f1, L_SEQ, D_INNER, D_MODEL, D_MODEL, 32);
    // 10. W2^T
    tr_cvt_kernel<<<dim3(D_MODEL / 32, D_INNER / 32), b32, 0, stream>>>(W2, W2T, D_INNER, D_MODEL);
    // 11. f2 partials = f1 @ W2 (split-K=2, f32 planes, no bias)  grid 8x8 x z=2
    gemm256<3><<<dim3(64, 1, 2), 512, 0, stream>>>(f1, W2T, nullptr, parts, L_SEQ, D_MODEL, D_INNER, D_INNER / 2, 8);
    // 12. out = LN(h + Σparts + b2)*g2+be2
    ln_part_kernel<<<L_SEQ, 256, 0, stream>>>(h, parts, 2, b2, g2, be2, (float*)d_out);
}